// Round 1
// baseline (206.331 us; speedup 1.0000x reference)
//
#include <hip/hip_runtime.h>

// DirectionalConv3d: B=8, C_IN=C_OUT=64, T=R=32, CO=32
// out[b,o,t,r,c] = sum over 7 taps (self, t+-1, r+-1, c+-1) of W_tap . x[b,:,shifted]
// Strategy: pass 1 transposes x -> xT[b, s, i] bf16 (+ bf16 weights) into d_ws,
// pass 2 is an LDS-free MFMA GEMM (M=s, N=o, K=448) with per-lane masked A loads.

#define SB 32768   // spatial per batch (T*R*CO)
#define CIN 64
#define COUT 64
#define NB 8

typedef short s16x8 __attribute__((ext_vector_type(8)));
typedef __bf16 bf16x8 __attribute__((ext_vector_type(8)));
typedef float f32x4 __attribute__((ext_vector_type(4)));

__device__ __forceinline__ unsigned short f2bf(float f) {
    unsigned u = __float_as_uint(f);
    u += 0x7FFFu + ((u >> 16) & 1u);   // round-to-nearest-even
    return (unsigned short)(u >> 16);
}

// ---------------- pass 1: transpose + cast ----------------
// blocks 0..1023: xT[b*SB + s][i] = bf16(x[b][i][s]); 256 s per block.
// blocks 1024..1030: weight tap repack to bf16 [tap][o][i].
__global__ void prep_kernel(const float* __restrict__ x,
                            const float* __restrict__ w0, const float* __restrict__ w1,
                            const float* __restrict__ w2, const float* __restrict__ w3,
                            const float* __restrict__ w4, const float* __restrict__ w5,
                            const float* __restrict__ w6,
                            unsigned short* __restrict__ ws) {
    int bid = blockIdx.x;
    int tid = threadIdx.x;
    if (bid < 1024) {
        int b = bid >> 7;
        int s = ((bid & 127) << 8) + tid;
        const float* xp = x + ((size_t)b * CIN) * SB + s;   // lane=s -> coalesced per i
        unsigned pack[32];
#pragma unroll
        for (int i = 0; i < 32; ++i) {
            float f0 = xp[(size_t)(2 * i) * SB];
            float f1 = xp[(size_t)(2 * i + 1) * SB];
            pack[i] = (unsigned)f2bf(f0) | ((unsigned)f2bf(f1) << 16);
        }
        unsigned short* row = ws + ((size_t)b * SB + s) * CIN;
        uint4* rp = (uint4*)row;
#pragma unroll
        for (int j = 0; j < 8; ++j)
            rp[j] = make_uint4(pack[4 * j], pack[4 * j + 1], pack[4 * j + 2], pack[4 * j + 3]);
    } else {
        int tap = bid - 1024;
        const float* w = (tap == 0) ? w0 : (tap == 1) ? w1 : (tap == 2) ? w2
                       : (tap == 3) ? w3 : (tap == 4) ? w4 : (tap == 5) ? w5 : w6;
        unsigned p[8];
#pragma unroll
        for (int j = 0; j < 8; ++j) {
            float f0 = w[tid * 16 + 2 * j];
            float f1 = w[tid * 16 + 2 * j + 1];
            p[j] = (unsigned)f2bf(f0) | ((unsigned)f2bf(f1) << 16);
        }
        unsigned short* dst = ws + (size_t)NB * SB * CIN + tap * 4096 + tid * 16;
        uint4* dp = (uint4*)dst;
        dp[0] = make_uint4(p[0], p[1], p[2], p[3]);
        dp[1] = make_uint4(p[4], p[5], p[6], p[7]);
    }
}

// ---------------- pass 2: MFMA GEMM ----------------
// WG = 256 thr = 4 waves; covers 64 o x 256 s for one b. Wave: 64 s x 64 o
// = 4x4 grid of 16x16 tiles, K=448 (7 taps x 64) via 16x16x32 bf16 MFMA.
__global__ __launch_bounds__(256) void gemm_kernel(const unsigned short* __restrict__ ws,
                                                   float* __restrict__ out) {
    const unsigned short* xq = ws;
    const unsigned short* wq = ws + (size_t)NB * SB * CIN;

    int bid = blockIdx.x;
    int b = bid >> 7;
    int sblk = (bid & 127) << 8;
    int tid = threadIdx.x;
    int lane = tid & 63;
    int wv = tid >> 6;
    int lo = lane & 15;
    int quad = lane >> 4;
    int sbase = sblk + wv * 64;
    int t = sbase >> 10;                 // uniform within block

    f32x4 acc[4][4];
#pragma unroll
    for (int mt = 0; mt < 4; ++mt)
#pragma unroll
        for (int nt = 0; nt < 4; ++nt)
            acc[mt][nt] = (f32x4){0.f, 0.f, 0.f, 0.f};

    int r_m[4], c_m[4];
    const unsigned short* arow[4];
#pragma unroll
    for (int mt = 0; mt < 4; ++mt) {
        int s = sbase + mt * 16 + lo;    // A row: m = lane&15
        r_m[mt] = (s >> 5) & 31;
        c_m[mt] = s & 31;
        arow[mt] = xq + ((size_t)b * SB + s) * CIN;
    }

#pragma unroll
    for (int tap = 0; tap < 7; ++tap) {
        const int d = (tap == 0) ? 0 : (tap == 1) ? -1024 : (tap == 2) ? 1024
                    : (tap == 3) ? -32 : (tap == 4) ? 32 : (tap == 5) ? -1 : 1;
        bool ok[4];
#pragma unroll
        for (int mt = 0; mt < 4; ++mt) {
            bool v = true;
            if (tap == 1) v = (t > 0);
            else if (tap == 2) v = (t < 31);
            else if (tap == 3) v = (r_m[mt] > 0);
            else if (tap == 4) v = (r_m[mt] < 31);
            else if (tap == 5) v = (c_m[mt] > 0);
            else if (tap == 6) v = (c_m[mt] < 31);
            ok[mt] = v;
        }
        const unsigned short* wt = wq + tap * 4096;
#pragma unroll
        for (int ks = 0; ks < 2; ++ks) {
            bf16x8 bf[4];
#pragma unroll
            for (int nt = 0; nt < 4; ++nt) {
                // B fragment: lane holds row o = nt*16+lo, k = ks*32 + quad*8 + j
                const unsigned short* bp = wt + (nt * 16 + lo) * 64 + ks * 32 + quad * 8;
                s16x8 raw = *(const s16x8*)bp;
                bf[nt] = __builtin_bit_cast(bf16x8, raw);
            }
#pragma unroll
            for (int mt = 0; mt < 4; ++mt) {
                const unsigned short* ap = arow[mt] + d * CIN + ks * 32 + quad * 8;
                ap = ok[mt] ? ap : xq;               // clamp: never deref OOB
                s16x8 raw = *(const s16x8*)ap;
                s16x8 zz = {0, 0, 0, 0, 0, 0, 0, 0};
                raw = ok[mt] ? raw : zz;
                bf16x8 af = __builtin_bit_cast(bf16x8, raw);
#pragma unroll
                for (int nt = 0; nt < 4; ++nt)
                    acc[mt][nt] = __builtin_amdgcn_mfma_f32_16x16x32_bf16(af, bf[nt], acc[mt][nt], 0, 0, 0);
            }
        }
    }

    // D layout: col(n=o) = lane&15, row(m=s) = quad*4 + reg -> 4 consecutive s
#pragma unroll
    for (int mt = 0; mt < 4; ++mt) {
#pragma unroll
        for (int nt = 0; nt < 4; ++nt) {
            int o = nt * 16 + lo;
            size_t off = ((size_t)(b * COUT + o)) * SB + sbase + mt * 16 + quad * 4;
            *(f32x4*)(out + off) = acc[mt][nt];
        }
    }
}

// ---------------- fallback (only if ws too small): fp32 direct ----------------
__global__ void fallback_kernel(const float* __restrict__ x,
                                const float* __restrict__ w0, const float* __restrict__ w1,
                                const float* __restrict__ w2, const float* __restrict__ w3,
                                const float* __restrict__ w4, const float* __restrict__ w5,
                                const float* __restrict__ w6,
                                float* __restrict__ out) {
    int bid = blockIdx.x;
    int b = bid >> 11;
    int og = (bid >> 7) & 15;
    int sblk = (bid & 127) << 8;
    int tid = threadIdx.x;
    __shared__ float wl[7][4][64];
    const float* wp[7] = {w0, w1, w2, w3, w4, w5, w6};
    for (int k = tid; k < 7 * 4 * 64; k += 256) {
        int tap = k >> 8, oo = (k >> 6) & 3, i = k & 63;
        wl[tap][oo][i] = wp[tap][(og * 4 + oo) * 64 + i];
    }
    __syncthreads();
    int s = sblk + tid;
    int t = s >> 10, r = (s >> 5) & 31, c = s & 31;
    const float* xb = x + (size_t)b * CIN * SB + s;
    float a0 = 0, a1 = 0, a2 = 0, a3 = 0;
    for (int i = 0; i < 64; ++i) {
        const float* xi = xb + (size_t)i * SB;
        float vs = xi[0];
        float vtp = (t > 0) ? xi[-1024] : 0.f;
        float vtm = (t < 31) ? xi[1024] : 0.f;
        float vrp = (r > 0) ? xi[-32] : 0.f;
        float vrm = (r < 31) ? xi[32] : 0.f;
        float vcp = (c > 0) ? xi[-1] : 0.f;
        float vcm = (c < 31) ? xi[1] : 0.f;
        a0 += wl[0][0][i] * vs + wl[1][0][i] * vtp + wl[2][0][i] * vtm + wl[3][0][i] * vrp + wl[4][0][i] * vrm + wl[5][0][i] * vcp + wl[6][0][i] * vcm;
        a1 += wl[0][1][i] * vs + wl[1][1][i] * vtp + wl[2][1][i] * vtm + wl[3][1][i] * vrp + wl[4][1][i] * vrm + wl[5][1][i] * vcp + wl[6][1][i] * vcm;
        a2 += wl[0][2][i] * vs + wl[1][2][i] * vtp + wl[2][2][i] * vtm + wl[3][2][i] * vrp + wl[4][2][i] * vrm + wl[5][2][i] * vcp + wl[6][2][i] * vcm;
        a3 += wl[0][3][i] * vs + wl[1][3][i] * vtp + wl[2][3][i] * vtm + wl[3][3][i] * vrp + wl[4][3][i] * vrm + wl[5][3][i] * vcp + wl[6][3][i] * vcm;
    }
    size_t obase = ((size_t)b * COUT + og * 4) * SB + s;
    out[obase] = a0;
    out[obase + SB] = a1;
    out[obase + 2 * (size_t)SB] = a2;
    out[obase + 3 * (size_t)SB] = a3;
}

extern "C" void kernel_launch(void* const* d_in, const int* in_sizes, int n_in,
                              void* d_out, int out_size, void* d_ws, size_t ws_size,
                              hipStream_t stream) {
    const float* x = (const float*)d_in[0];
    const float* w0 = (const float*)d_in[1];
    const float* w1 = (const float*)d_in[2];
    const float* w2 = (const float*)d_in[3];
    const float* w3 = (const float*)d_in[4];
    const float* w4 = (const float*)d_in[5];
    const float* w5 = (const float*)d_in[6];
    const float* w6 = (const float*)d_in[7];
    float* out = (float*)d_out;

    size_t need = (size_t)NB * SB * CIN * 2 + (size_t)7 * 4096 * 2;
    if (d_ws != nullptr && ws_size >= need) {
        unsigned short* wsp = (unsigned short*)d_ws;
        prep_kernel<<<1031, 256, 0, stream>>>(x, w0, w1, w2, w3, w4, w5, w6, wsp);
        gemm_kernel<<<1024, 256, 0, stream>>>(wsp, out);
    } else {
        fallback_kernel<<<8 * 16 * 128, 256, 0, stream>>>(x, w0, w1, w2, w3, w4, w5, w6, out);
    }
}

// Round 2
// 175.895 us; speedup vs baseline: 1.1730x; 1.1730x over previous
//
#include <hip/hip_runtime.h>

// DirectionalConv3d: B=8, C_IN=C_OUT=64, T=R=32, CO=32
// Pass 1: transpose+cast x -> xT[b,s,i] bf16 via LDS (coalesced writes), + bf16 weights.
// Pass 2: MFMA GEMM; A-fragments for self/r+-/c+- taps from a 40KB xor-swizzled LDS
// tile (rows sblk-32..sblk+288); t+- taps from global (block-uniform mask).

#define SB 32768   // spatial per batch (T*R*CO)
#define CIN 64
#define COUT 64
#define NB 8

typedef short s16x8 __attribute__((ext_vector_type(8)));
typedef __bf16 bf16x8 __attribute__((ext_vector_type(8)));
typedef float f32x4 __attribute__((ext_vector_type(4)));

__device__ __forceinline__ unsigned short f2bf(float f) {
    unsigned u = __float_as_uint(f);
    u += 0x7FFFu + ((u >> 16) & 1u);   // round-to-nearest-even
    return (unsigned short)(u >> 16);
}

// ---------------- pass 1: transpose + cast ----------------
// blocks 0..1023: xT[b*SB + s][i] = bf16(x[b][i][s]); 256 s per block, LDS transpose.
// blocks 1024..1030: weight tap repack to bf16 [tap][o][i].
__global__ __launch_bounds__(256) void prep_kernel(const float* __restrict__ x,
                            const float* __restrict__ w0, const float* __restrict__ w1,
                            const float* __restrict__ w2, const float* __restrict__ w3,
                            const float* __restrict__ w4, const float* __restrict__ w5,
                            const float* __restrict__ w6,
                            unsigned short* __restrict__ ws) {
    __shared__ uint4 lds[2048];   // 32 KB: chunk (row,j) at phys row*8 + (j^(row&7))
    int bid = blockIdx.x;
    int tid = threadIdx.x;
    if (bid < 1024) {
        int b = bid >> 7;
        int sblk = (bid & 127) << 8;
        const float* xp = x + ((size_t)b * CIN) * SB + sblk + tid;  // lane=s -> coalesced per i
        unsigned pack[32];
#pragma unroll
        for (int i = 0; i < 32; ++i) {
            float f0 = xp[(size_t)(2 * i) * SB];
            float f1 = xp[(size_t)(2 * i + 1) * SB];
            pack[i] = (unsigned)f2bf(f0) | ((unsigned)f2bf(f1) << 16);
        }
#pragma unroll
        for (int j = 0; j < 8; ++j)
            lds[tid * 8 + (j ^ (tid & 7))] =
                make_uint4(pack[4 * j], pack[4 * j + 1], pack[4 * j + 2], pack[4 * j + 3]);
        __syncthreads();
        uint4* dst = (uint4*)(ws + ((size_t)b * SB + sblk) * CIN);
#pragma unroll
        for (int k = 0; k < 8; ++k) {
            int q = k * 256 + tid;            // consecutive lanes -> consecutive 16B: coalesced
            int row = q >> 3, j = q & 7;
            dst[q] = lds[row * 8 + (j ^ (row & 7))];
        }
    } else {
        int tap = bid - 1024;
        const float* w = (tap == 0) ? w0 : (tap == 1) ? w1 : (tap == 2) ? w2
                       : (tap == 3) ? w3 : (tap == 4) ? w4 : (tap == 5) ? w5 : w6;
        unsigned p[8];
#pragma unroll
        for (int j = 0; j < 8; ++j) {
            float f0 = w[tid * 16 + 2 * j];
            float f1 = w[tid * 16 + 2 * j + 1];
            p[j] = (unsigned)f2bf(f0) | ((unsigned)f2bf(f1) << 16);
        }
        unsigned short* dst = ws + (size_t)NB * SB * CIN + tap * 4096 + tid * 16;
        uint4* dp = (uint4*)dst;
        dp[0] = make_uint4(p[0], p[1], p[2], p[3]);
        dp[1] = make_uint4(p[4], p[5], p[6], p[7]);
    }
}

// ---------------- pass 2: MFMA GEMM ----------------
// WG = 256 thr = 4 waves; 64 o x 256 s per block. Wave: 64 s x 64 o = 4x4 grid of
// 16x16 tiles, K=448 (7 taps x 64) via 16x16x32 bf16 MFMA.
__global__ __launch_bounds__(256, 4) void gemm_kernel(const unsigned short* __restrict__ ws,
                                                      float* __restrict__ out) {
    __shared__ uint4 alds[2560];  // 40 KB: rows sblk-32 .. sblk+288, xor-swizzled 16B chunks
    const unsigned short* xq = ws;
    const unsigned short* wq = ws + (size_t)NB * SB * CIN;

    int bid = blockIdx.x;
    int b = bid >> 7;
    int sblk = (bid & 127) << 8;
    int tid = threadIdx.x;

    // ---- stage A tile (center + r-halo) into LDS, coalesced 16B chunks ----
    const uint4* xu = (const uint4*)(xq + (size_t)b * SB * CIN);
#pragma unroll
    for (int k = 0; k < 10; ++k) {
        int q = k * 256 + tid;               // 2560 chunks
        int row = q >> 3, j = q & 7;         // row 0..319
        int s = sblk - 32 + row;
        s = max(0, min(SB - 1, s));          // clamped rows only feed masked lanes
        alds[row * 8 + (j ^ (row & 7))] = xu[(size_t)s * 8 + j];
    }
    __syncthreads();

    int lane = tid & 63;
    int wv = tid >> 6;
    int lo = lane & 15;
    int quad = lane >> 4;
    int sbase = sblk + wv * 64;
    int t = sblk >> 10;                      // uniform within block

    f32x4 acc[4][4];
#pragma unroll
    for (int mt = 0; mt < 4; ++mt)
#pragma unroll
        for (int nt = 0; nt < 4; ++nt)
            acc[mt][nt] = (f32x4){0.f, 0.f, 0.f, 0.f};

    int r_m[4], c_m[4], rl[4];
#pragma unroll
    for (int mt = 0; mt < 4; ++mt) {
        int s = sbase + mt * 16 + lo;        // A row: m = lane&15
        r_m[mt] = (s >> 5) & 31;
        c_m[mt] = s & 31;
        rl[mt] = s - sblk + 32;              // LDS row_local
    }

    auto load_b = [&](const unsigned short* wt, int ks, int nt) -> bf16x8 {
        const unsigned short* bp = wt + (nt * 16 + lo) * 64 + ks * 32 + quad * 8;
        return __builtin_bit_cast(bf16x8, *(const s16x8*)bp);
    };

    // taps read from LDS (self, r+-, c+-) with per-lane mask
    auto run_tap_lds = [&](int tap, int d, const bool ok[4]) {
        const unsigned short* wt = wq + tap * 4096;
#pragma unroll
        for (int ks = 0; ks < 2; ++ks) {
            bf16x8 bf[4];
#pragma unroll
            for (int nt = 0; nt < 4; ++nt) bf[nt] = load_b(wt, ks, nt);
            int j = ks * 4 + quad;
#pragma unroll
            for (int mt = 0; mt < 4; ++mt) {
                int row = rl[mt] + d;        // always in [0,320)
                s16x8 raw = *((const s16x8*)alds + row * 8 + (j ^ (row & 7)));
                s16x8 zz = {0, 0, 0, 0, 0, 0, 0, 0};
                raw = ok[mt] ? raw : zz;
                bf16x8 af = __builtin_bit_cast(bf16x8, raw);
#pragma unroll
                for (int nt = 0; nt < 4; ++nt)
                    acc[mt][nt] = __builtin_amdgcn_mfma_f32_16x16x32_bf16(af, bf[nt], acc[mt][nt], 0, 0, 0);
            }
        }
    };

    // t+-1 taps: block-uniform validity, A from global (coalesced 16-line gathers)
    auto run_tap_glb = [&](int tap, int d) {
        const unsigned short* wt = wq + tap * 4096;
#pragma unroll
        for (int ks = 0; ks < 2; ++ks) {
            bf16x8 bf[4];
#pragma unroll
            for (int nt = 0; nt < 4; ++nt) bf[nt] = load_b(wt, ks, nt);
#pragma unroll
            for (int mt = 0; mt < 4; ++mt) {
                int s = sbase + mt * 16 + lo + d;
                const unsigned short* ap = xq + ((size_t)b * SB + s) * CIN + ks * 32 + quad * 8;
                bf16x8 af = __builtin_bit_cast(bf16x8, *(const s16x8*)ap);
#pragma unroll
                for (int nt = 0; nt < 4; ++nt)
                    acc[mt][nt] = __builtin_amdgcn_mfma_f32_16x16x32_bf16(af, bf[nt], acc[mt][nt], 0, 0, 0);
            }
        }
    };

    {
        bool ok_all[4] = {true, true, true, true};
        run_tap_lds(0, 0, ok_all);                 // self
    }
    if (t > 0)  run_tap_glb(1, -1024);             // t-1
    if (t < 31) run_tap_glb(2, 1024);              // t+1
    {
        bool ok[4];
#pragma unroll
        for (int mt = 0; mt < 4; ++mt) ok[mt] = (r_m[mt] > 0);
        run_tap_lds(3, -32, ok);                   // r-1
#pragma unroll
        for (int mt = 0; mt < 4; ++mt) ok[mt] = (r_m[mt] < 31);
        run_tap_lds(4, 32, ok);                    // r+1
#pragma unroll
        for (int mt = 0; mt < 4; ++mt) ok[mt] = (c_m[mt] > 0);
        run_tap_lds(5, -1, ok);                    // c-1
#pragma unroll
        for (int mt = 0; mt < 4; ++mt) ok[mt] = (c_m[mt] < 31);
        run_tap_lds(6, 1, ok);                     // c+1
    }

    // D layout: col(n=o) = lane&15, row(m=s) = quad*4 + reg -> 4 consecutive s
#pragma unroll
    for (int mt = 0; mt < 4; ++mt) {
#pragma unroll
        for (int nt = 0; nt < 4; ++nt) {
            int o = nt * 16 + lo;
            size_t off = ((size_t)(b * COUT + o)) * SB + sbase + mt * 16 + quad * 4;
            *(f32x4*)(out + off) = acc[mt][nt];
        }
    }
}

// ---------------- fallback (only if ws too small): fp32 direct ----------------
__global__ void fallback_kernel(const float* __restrict__ x,
                                const float* __restrict__ w0, const float* __restrict__ w1,
                                const float* __restrict__ w2, const float* __restrict__ w3,
                                const float* __restrict__ w4, const float* __restrict__ w5,
                                const float* __restrict__ w6,
                                float* __restrict__ out) {
    int bid = blockIdx.x;
    int b = bid >> 11;
    int og = (bid >> 7) & 15;
    int sblk = (bid & 127) << 8;
    int tid = threadIdx.x;
    __shared__ float wl[7][4][64];
    const float* wp[7] = {w0, w1, w2, w3, w4, w5, w6};
    for (int k = tid; k < 7 * 4 * 64; k += 256) {
        int tap = k >> 8, oo = (k >> 6) & 3, i = k & 63;
        wl[tap][oo][i] = wp[tap][(og * 4 + oo) * 64 + i];
    }
    __syncthreads();
    int s = sblk + tid;
    int t = s >> 10, r = (s >> 5) & 31, c = s & 31;
    const float* xb = x + (size_t)b * CIN * SB + s;
    float a0 = 0, a1 = 0, a2 = 0, a3 = 0;
    for (int i = 0; i < 64; ++i) {
        const float* xi = xb + (size_t)i * SB;
        float vs = xi[0];
        float vtp = (t > 0) ? xi[-1024] : 0.f;
        float vtm = (t < 31) ? xi[1024] : 0.f;
        float vrp = (r > 0) ? xi[-32] : 0.f;
        float vrm = (r < 31) ? xi[32] : 0.f;
        float vcp = (c > 0) ? xi[-1] : 0.f;
        float vcm = (c < 31) ? xi[1] : 0.f;
        a0 += wl[0][0][i] * vs + wl[1][0][i] * vtp + wl[2][0][i] * vtm + wl[3][0][i] * vrp + wl[4][0][i] * vrm + wl[5][0][i] * vcp + wl[6][0][i] * vcm;
        a1 += wl[0][1][i] * vs + wl[1][1][i] * vtp + wl[2][1][i] * vtm + wl[3][1][i] * vrp + wl[4][1][i] * vrm + wl[5][1][i] * vcp + wl[6][1][i] * vcm;
        a2 += wl[0][2][i] * vs + wl[1][2][i] * vtp + wl[2][2][i] * vtm + wl[3][2][i] * vrp + wl[4][2][i] * vrm + wl[5][2][i] * vcp + wl[6][2][i] * vcm;
        a3 += wl[0][3][i] * vs + wl[1][3][i] * vtp + wl[2][3][i] * vtm + wl[3][3][i] * vrp + wl[4][3][i] * vrm + wl[5][3][i] * vcp + wl[6][3][i] * vcm;
    }
    size_t obase = ((size_t)b * COUT + og * 4) * SB + s;
    out[obase] = a0;
    out[obase + SB] = a1;
    out[obase + 2 * (size_t)SB] = a2;
    out[obase + 3 * (size_t)SB] = a3;
}

extern "C" void kernel_launch(void* const* d_in, const int* in_sizes, int n_in,
                              void* d_out, int out_size, void* d_ws, size_t ws_size,
                              hipStream_t stream) {
    const float* x = (const float*)d_in[0];
    const float* w0 = (const float*)d_in[1];
    const float* w1 = (const float*)d_in[2];
    const float* w2 = (const float*)d_in[3];
    const float* w3 = (const float*)d_in[4];
    const float* w4 = (const float*)d_in[5];
    const float* w5 = (const float*)d_in[6];
    const float* w6 = (const float*)d_in[7];
    float* out = (float*)d_out;

    size_t need = (size_t)NB * SB * CIN * 2 + (size_t)7 * 4096 * 2;
    if (d_ws != nullptr && ws_size >= need) {
        unsigned short* wsp = (unsigned short*)d_ws;
        prep_kernel<<<1031, 256, 0, stream>>>(x, w0, w1, w2, w3, w4, w5, w6, wsp);
        gemm_kernel<<<1024, 256, 0, stream>>>(wsp, out);
    } else {
        fallback_kernel<<<8 * 16 * 128, 256, 0, stream>>>(x, w0, w1, w2, w3, w4, w5, w6, out);
    }
}

// Round 3
// 159.025 us; speedup vs baseline: 1.2975x; 1.1061x over previous
//
#include <hip/hip_runtime.h>

// DirectionalConv3d: B=8, C_IN=C_OUT=64, T=R=32, CO=32
// Fused design: one MFMA kernel reads fp32 x directly.
//  - center + r/c-halo rows (320) staged as bf16 into 40KB xor-swizzled LDS
//    (per-thread row ownership: strided scalar reads, conflict-free b128 writes)
//  - t+-1 taps: A-fragments gathered straight from fp32 x (8 strided loads + pack),
//    block-uniform validity
//  - weights converted once to bf16 by a tiny wprep kernel into d_ws (56KB)

#define SB 32768   // spatial per batch (T*R*CO)
#define CIN 64
#define COUT 64
#define NB 8

typedef short s16x8 __attribute__((ext_vector_type(8)));
typedef __bf16 bf16x8 __attribute__((ext_vector_type(8)));
typedef float f32x4 __attribute__((ext_vector_type(4)));

__device__ __forceinline__ unsigned f2bf(float f) {
    unsigned u = __float_as_uint(f);
    u += 0x7FFFu + ((u >> 16) & 1u);   // round-to-nearest-even
    return u >> 16;
}
__device__ __forceinline__ unsigned pk2(float lo, float hi) {
    return f2bf(lo) | (f2bf(hi) << 16);
}

// ---------------- weight prep: fp32 -> bf16, [tap][o][i] ----------------
__global__ __launch_bounds__(256) void wprep_kernel(const float* __restrict__ w0,
                            const float* __restrict__ w1, const float* __restrict__ w2,
                            const float* __restrict__ w3, const float* __restrict__ w4,
                            const float* __restrict__ w5, const float* __restrict__ w6,
                            unsigned short* __restrict__ ws) {
    int tap = blockIdx.x;
    int tid = threadIdx.x;
    const float* w = (tap == 0) ? w0 : (tap == 1) ? w1 : (tap == 2) ? w2
                   : (tap == 3) ? w3 : (tap == 4) ? w4 : (tap == 5) ? w5 : w6;
    unsigned p[8];
#pragma unroll
    for (int j = 0; j < 8; ++j)
        p[j] = pk2(w[tid * 16 + 2 * j], w[tid * 16 + 2 * j + 1]);
    uint4* dp = (uint4*)(ws + tap * 4096 + tid * 16);
    dp[0] = make_uint4(p[0], p[1], p[2], p[3]);
    dp[1] = make_uint4(p[4], p[5], p[6], p[7]);
}

// ---------------- fused conv kernel ----------------
// grid 1024 = 8 b x 128 s-tiles of 256. Block 256 thr = 4 waves; wave: 64 s x 64 o
// = 4x4 grid of 16x16 tiles, K=448 via mfma_f32_16x16x32_bf16.
__global__ __launch_bounds__(256) void conv_kernel(const float* __restrict__ x,
                                                   const unsigned short* __restrict__ wq,
                                                   float* __restrict__ out) {
    __shared__ uint4 alds[2560];  // 40 KB: rows sblk-32 .. sblk+288, 16B-chunk xor swizzle
    int bid = blockIdx.x;
    int b = bid >> 7;
    int sblk = (bid & 127) << 8;
    int tid = threadIdx.x;
    const float* xb = x + (size_t)b * CIN * SB;

    // ---- stage center rows: thread owns row s = sblk+tid ----
    {
        int rl = 32 + tid;
        const float* xp = xb + sblk + tid;     // lanes: consecutive s -> coalesced per i
#pragma unroll
        for (int c = 0; c < 4; ++c) {          // 16 channels per chunk
            unsigned pk[8];
#pragma unroll
            for (int u = 0; u < 8; ++u)
                pk[u] = pk2(xp[(size_t)(c * 16 + 2 * u) * SB],
                            xp[(size_t)(c * 16 + 2 * u + 1) * SB]);
            alds[rl * 8 + ((2 * c) ^ (rl & 7))] = make_uint4(pk[0], pk[1], pk[2], pk[3]);
            alds[rl * 8 + ((2 * c + 1) ^ (rl & 7))] = make_uint4(pk[4], pk[5], pk[6], pk[7]);
        }
    }
    // ---- stage r-halo rows (64 rows x 64 ch): wave w does channels 16w..16w+15 ----
    {
        int hrow = tid & 63;
        int rl = (hrow < 32) ? hrow : hrow + 256;   // 0..31, 288..319
        int s = sblk - 32 + rl;
        s = max(0, min(SB - 1, s));                 // clamped rows feed masked lanes only
        int ic = tid >> 6;
        const float* xp = xb + s + (size_t)(ic * 16) * SB;
        unsigned pk[8];
#pragma unroll
        for (int u = 0; u < 8; ++u)
            pk[u] = pk2(xp[(size_t)(2 * u) * SB], xp[(size_t)(2 * u + 1) * SB]);
        alds[rl * 8 + ((2 * ic) ^ (rl & 7))] = make_uint4(pk[0], pk[1], pk[2], pk[3]);
        alds[rl * 8 + ((2 * ic + 1) ^ (rl & 7))] = make_uint4(pk[4], pk[5], pk[6], pk[7]);
    }
    __syncthreads();

    int lane = tid & 63;
    int wv = tid >> 6;
    int lo = lane & 15;
    int quad = lane >> 4;
    int sbase = sblk + wv * 64;
    int t = sblk >> 10;                      // uniform within block

    f32x4 acc[4][4];
#pragma unroll
    for (int mt = 0; mt < 4; ++mt)
#pragma unroll
        for (int nt = 0; nt < 4; ++nt)
            acc[mt][nt] = (f32x4){0.f, 0.f, 0.f, 0.f};

    int r_m[4], c_m[4], rl[4];
#pragma unroll
    for (int mt = 0; mt < 4; ++mt) {
        int s = sbase + mt * 16 + lo;        // A row: m = lane&15
        r_m[mt] = (s >> 5) & 31;
        c_m[mt] = s & 31;
        rl[mt] = s - sblk + 32;              // LDS row_local
    }

    auto load_b = [&](const unsigned short* wt, int ks, int nt) -> bf16x8 {
        const unsigned short* bp = wt + (nt * 16 + lo) * 64 + ks * 32 + quad * 8;
        return __builtin_bit_cast(bf16x8, *(const s16x8*)bp);
    };

    // taps reading the LDS tile (self, r+-, c+-), per-lane mask
    auto run_tap_lds = [&](int tap, int d, const bool ok[4]) {
        const unsigned short* wt = wq + tap * 4096;
#pragma unroll
        for (int ks = 0; ks < 2; ++ks) {
            bf16x8 bf[4];
#pragma unroll
            for (int nt = 0; nt < 4; ++nt) bf[nt] = load_b(wt, ks, nt);
            int j = ks * 4 + quad;
#pragma unroll
            for (int mt = 0; mt < 4; ++mt) {
                int row = rl[mt] + d;        // always in [0,320)
                s16x8 raw = *((const s16x8*)alds + row * 8 + (j ^ (row & 7)));
                s16x8 zz = {0, 0, 0, 0, 0, 0, 0, 0};
                raw = ok[mt] ? raw : zz;
                bf16x8 af = __builtin_bit_cast(bf16x8, raw);
#pragma unroll
                for (int nt = 0; nt < 4; ++nt)
                    acc[mt][nt] = __builtin_amdgcn_mfma_f32_16x16x32_bf16(af, bf[nt], acc[mt][nt], 0, 0, 0);
            }
        }
    };

    // t+-1 taps: block-uniform validity; A-fragment gathered from fp32 x
    auto run_tap_gather = [&](int tap, int d) {
        const unsigned short* wt = wq + tap * 4096;
#pragma unroll
        for (int ks = 0; ks < 2; ++ks) {
            bf16x8 bf[4];
#pragma unroll
            for (int nt = 0; nt < 4; ++nt) bf[nt] = load_b(wt, ks, nt);
            const float* gp = xb + (size_t)(ks * 32 + quad * 8) * SB + d;
#pragma unroll
            for (int mt = 0; mt < 4; ++mt) {
                const float* ap = gp + sbase + mt * 16 + lo;
                unsigned pk[4];
#pragma unroll
                for (int u = 0; u < 4; ++u)
                    pk[u] = pk2(ap[(size_t)(2 * u) * SB], ap[(size_t)(2 * u + 1) * SB]);
                uint4 v = make_uint4(pk[0], pk[1], pk[2], pk[3]);
                bf16x8 af = __builtin_bit_cast(bf16x8, v);
#pragma unroll
                for (int nt = 0; nt < 4; ++nt)
                    acc[mt][nt] = __builtin_amdgcn_mfma_f32_16x16x32_bf16(af, bf[nt], acc[mt][nt], 0, 0, 0);
            }
        }
    };

    {
        bool ok_all[4] = {true, true, true, true};
        run_tap_lds(0, 0, ok_all);                 // self
    }
    if (t > 0)  run_tap_gather(1, -1024);          // t-1
    if (t < 31) run_tap_gather(2, 1024);           // t+1
    {
        bool ok[4];
#pragma unroll
        for (int mt = 0; mt < 4; ++mt) ok[mt] = (r_m[mt] > 0);
        run_tap_lds(3, -32, ok);                   // r-1
#pragma unroll
        for (int mt = 0; mt < 4; ++mt) ok[mt] = (r_m[mt] < 31);
        run_tap_lds(4, 32, ok);                    // r+1
#pragma unroll
        for (int mt = 0; mt < 4; ++mt) ok[mt] = (c_m[mt] > 0);
        run_tap_lds(5, -1, ok);                    // c-1
#pragma unroll
        for (int mt = 0; mt < 4; ++mt) ok[mt] = (c_m[mt] < 31);
        run_tap_lds(6, 1, ok);                     // c+1
    }

    // D layout: col(n=o) = lane&15, row(m=s) = quad*4 + reg -> full 64B lines per wave
#pragma unroll
    for (int mt = 0; mt < 4; ++mt) {
#pragma unroll
        for (int nt = 0; nt < 4; ++nt) {
            int o = nt * 16 + lo;
            size_t off = ((size_t)(b * COUT + o)) * SB + sbase + mt * 16 + quad * 4;
            *(f32x4*)(out + off) = acc[mt][nt];
        }
    }
}

// ---------------- fallback (only if ws too small): fp32 direct ----------------
__global__ void fallback_kernel(const float* __restrict__ x,
                                const float* __restrict__ w0, const float* __restrict__ w1,
                                const float* __restrict__ w2, const float* __restrict__ w3,
                                const float* __restrict__ w4, const float* __restrict__ w5,
                                const float* __restrict__ w6,
                                float* __restrict__ out) {
    int bid = blockIdx.x;
    int b = bid >> 11;
    int og = (bid >> 7) & 15;
    int sblk = (bid & 127) << 8;
    int tid = threadIdx.x;
    __shared__ float wl[7][4][64];
    const float* wp[7] = {w0, w1, w2, w3, w4, w5, w6};
    for (int k = tid; k < 7 * 4 * 64; k += 256) {
        int tap = k >> 8, oo = (k >> 6) & 3, i = k & 63;
        wl[tap][oo][i] = wp[tap][(og * 4 + oo) * 64 + i];
    }
    __syncthreads();
    int s = sblk + tid;
    int t = s >> 10, r = (s >> 5) & 31, c = s & 31;
    const float* xb = x + (size_t)b * CIN * SB + s;
    float a0 = 0, a1 = 0, a2 = 0, a3 = 0;
    for (int i = 0; i < 64; ++i) {
        const float* xi = xb + (size_t)i * SB;
        float vs = xi[0];
        float vtp = (t > 0) ? xi[-1024] : 0.f;
        float vtm = (t < 31) ? xi[1024] : 0.f;
        float vrp = (r > 0) ? xi[-32] : 0.f;
        float vrm = (r < 31) ? xi[32] : 0.f;
        float vcp = (c > 0) ? xi[-1] : 0.f;
        float vcm = (c < 31) ? xi[1] : 0.f;
        a0 += wl[0][0][i] * vs + wl[1][0][i] * vtp + wl[2][0][i] * vtm + wl[3][0][i] * vrp + wl[4][0][i] * vrm + wl[5][0][i] * vcp + wl[6][0][i] * vcm;
        a1 += wl[0][1][i] * vs + wl[1][1][i] * vtp + wl[2][1][i] * vtm + wl[3][1][i] * vrp + wl[4][1][i] * vrm + wl[5][1][i] * vcp + wl[6][1][i] * vcm;
        a2 += wl[0][2][i] * vs + wl[1][2][i] * vtp + wl[2][2][i] * vtm + wl[3][2][i] * vrp + wl[4][2][i] * vrm + wl[5][2][i] * vcp + wl[6][2][i] * vcm;
        a3 += wl[0][3][i] * vs + wl[1][3][i] * vtp + wl[2][3][i] * vtm + wl[3][3][i] * vrp + wl[4][3][i] * vrm + wl[5][3][i] * vcp + wl[6][3][i] * vcm;
    }
    size_t obase = ((size_t)b * COUT + og * 4) * SB + s;
    out[obase] = a0;
    out[obase + SB] = a1;
    out[obase + 2 * (size_t)SB] = a2;
    out[obase + 3 * (size_t)SB] = a3;
}

extern "C" void kernel_launch(void* const* d_in, const int* in_sizes, int n_in,
                              void* d_out, int out_size, void* d_ws, size_t ws_size,
                              hipStream_t stream) {
    const float* x = (const float*)d_in[0];
    const float* w0 = (const float*)d_in[1];
    const float* w1 = (const float*)d_in[2];
    const float* w2 = (const float*)d_in[3];
    const float* w3 = (const float*)d_in[4];
    const float* w4 = (const float*)d_in[5];
    const float* w5 = (const float*)d_in[6];
    const float* w6 = (const float*)d_in[7];
    float* out = (float*)d_out;

    size_t need = (size_t)7 * 4096 * 2;   // bf16 weights only: 56 KB
    if (d_ws != nullptr && ws_size >= need) {
        unsigned short* wsp = (unsigned short*)d_ws;
        wprep_kernel<<<7, 256, 0, stream>>>(w0, w1, w2, w3, w4, w5, w6, wsp);
        conv_kernel<<<1024, 256, 0, stream>>>(x, wsp, out);
    } else {
        fallback_kernel<<<8 * 16 * 128, 256, 0, stream>>>(x, w0, w1, w2, w3, w4, w5, w6, out);
    }
}